// Round 12
// baseline (361.992 us; speedup 1.0000x reference)
//
#include <hip/hip_runtime.h>
#include <hip/hip_bf16.h>

using f32x4 = __attribute__((ext_vector_type(4))) float;
using s16x8 = __attribute__((ext_vector_type(8))) short;
using i32x4 = __attribute__((ext_vector_type(4))) int;

#define NTOT 16384
#define NUSER 8192
#define DIM 256

__device__ __forceinline__ unsigned short f2bf(float f) {
  union { float f; unsigned u; } v; v.f = f;
  unsigned r = v.u + 0x7FFFu + ((v.u >> 16) & 1u);   // RNE
  return (unsigned short)(r >> 16);
}

__device__ __forceinline__ unsigned pack2bf(float x, float y) {
  float2 t; t.x = x; t.y = y;
  __hip_bfloat162 h = __float22bfloat162_rn(t);
  union { __hip_bfloat162 h; unsigned u; } cv; cv.h = h;
  return cv.u;
}

__device__ __forceinline__ void gload_lds16(const void* g, void* l) {
  __builtin_amdgcn_global_load_lds(
      (const __attribute__((address_space(1))) unsigned int*)g,
      (__attribute__((address_space(3))) unsigned int*)l, 16, 0, 0);
}

// ---------------- transpose + f32->bf16: dst[N][K] = src[K][N] ----------------
__global__ __launch_bounds__(256) void transpose_cvt(const float* __restrict__ src,
                                                     unsigned short* __restrict__ dst,
                                                     int K, int N) {
  __shared__ float tile[64][65];
  const int k0 = blockIdx.x * 64, n0 = blockIdx.y * 64;
  const int t = threadIdx.x;
#pragma unroll
  for (int i = 0; i < 16; i++) {
    int idx = i * 256 + t, r = idx >> 6, c = idx & 63;
    tile[r][c] = src[(size_t)(k0 + r) * N + n0 + c];
  }
  __syncthreads();
#pragma unroll
  for (int i = 0; i < 16; i++) {
    int idx = i * 256 + t, r = idx >> 6, c = idx & 63;
    dst[(size_t)(n0 + r) * K + k0 + c] = f2bf(tile[c][r]);
  }
}

// 5 square 256x256 weights in one launch
__global__ __launch_bounds__(256) void transpose_w5(const float* __restrict__ w0,
                                                    const float* __restrict__ w1,
                                                    const float* __restrict__ w2,
                                                    const float* __restrict__ w3,
                                                    const float* __restrict__ w4,
                                                    unsigned short* __restrict__ dstbase) {
  __shared__ float tile[64][65];
  const float* srcs[5] = {w0, w1, w2, w3, w4};
  const float* src = srcs[blockIdx.z];
  unsigned short* dst = dstbase + (size_t)blockIdx.z * 65536;
  const int k0 = blockIdx.x * 64, n0 = blockIdx.y * 64;
  const int t = threadIdx.x;
#pragma unroll
  for (int i = 0; i < 16; i++) {
    int idx = i * 256 + t, r = idx >> 6, c = idx & 63;
    tile[r][c] = src[(size_t)(k0 + r) * 256 + n0 + c];
  }
  __syncthreads();
#pragma unroll
  for (int i = 0; i < 16; i++) {
    int idx = i * 256 + t, r = idx >> 6, c = idx & 63;
    dst[(size_t)(n0 + r) * 256 + k0 + c] = f2bf(tile[c][r]);
  }
}

// ---------------- gemm1 v12: F1p[s] = A[:, sK:] @ feat[sK:, :] ---------------
// BM=128, BN=256, split-K=2, XCD-L2-resident B. A staged in 128-col chunks
// (512-B DRAM strips). 2-buffer A + 2-buffer B, top-of-phase B issue,
// A issued at ODD steps after B so barriers never drain needed work:
// odd barrier vmcnt(8) keeps A; even barrier vmcnt(0) has only fresh B.
struct AChunk { f32x4 v[8]; };

__global__ __launch_bounds__(512) void gemm1(const float* __restrict__ A,
                                             const unsigned short* __restrict__ Ft,
                                             float* __restrict__ F1p) {
  __shared__ char smem[128 * 1024];
  char* const Ab0 = smem;                 // [128 rows][256 B] bf16, 32 KB each
  char* const Ab1 = smem + 32 * 1024;
  char* const Bb0 = smem + 64 * 1024;     // [256][64] bf16, 32 KB each
  char* const Bb1 = smem + 96 * 1024;

  const int tid = threadIdx.x;
  const int l = tid & 63, w = tid >> 6;
  const int wm = w >> 2, wn = w & 3;      // 2x4 waves, wave tile 64x64
  const int lr = l & 15, lk = l >> 4;

  const int lin = blockIdx.x;             // 0..255
  const int xcd = lin & 7, slot = lin >> 3;   // slot 0..31
  const int ks = xcd >> 2;                // 0..1
  const int mblk = (xcd & 3) * 32 + slot; // 0..127
  const int m0 = mblk * 128;
  const size_t ks0 = (size_t)ks * 8192;
  float* out = F1p + (size_t)ks * NTOT * DIM;

  // A staging: chunk = 128 rows x 128 f32 cols (512 B/row strip).
  const int arow = tid >> 4, ac16 = tid & 15;   // row-in-32, 16B chunk id
  const float* asrc = A + (size_t)(m0 + arow) * NTOT + ks0 + ac16 * 4;
  int aoffb[4][2];   // LDS byte offsets per (row-group j, col-block c)
#pragma unroll
  for (int j = 0; j < 4; j++) {
    int r = j * 32 + arow;
#pragma unroll
    for (int c = 0; c < 2; c++)
      aoffb[j][c] = r * 256 + ((c * 128 + ac16 * 8) ^ ((r & 7) << 4));
  }

  // B staging via global_load_lds: per wave 4 x 1KB (rows w*32..w*32+31)
  const int brin = l >> 3;
  const int bldso = w * 4096;
  const char* bsrc = (const char*)Ft + (size_t)(w * 32 + brin) * (NTOT * 2) +
                     ks0 * 2 + (((l & 7) * 16) ^ (brin << 4));

  f32x4 zero = {0.f, 0.f, 0.f, 0.f};
  f32x4 acc[4][4];
#pragma unroll
  for (int i = 0; i < 4; i++)
#pragma unroll
    for (int j = 0; j < 4; j++) acc[i][j] = zero;

  AChunk avP, avQ;   // avP: even chunks, avQ: odd chunks

  auto issueB = [&](int t, char* Bb) {
#pragma unroll
    for (int i = 0; i < 4; i++)
      gload_lds16(bsrc + (size_t)i * 8 * (NTOT * 2) + t * 128,
                  Bb + bldso + i * 1024);
  };
  auto issueA = [&](int u, AChunk& s) {
#pragma unroll
    for (int j = 0; j < 4; j++)
#pragma unroll
      for (int c = 0; c < 2; c++)
        s.v[j * 2 + c] = __builtin_nontemporal_load(
            (const f32x4*)(asrc + (size_t)j * 32 * NTOT + u * 128 + c * 64));
  };
  auto writeA = [&](const AChunk& s, char* Ab) {
#pragma unroll
    for (int j = 0; j < 4; j++)
#pragma unroll
      for (int c = 0; c < 2; c++) {
        unsigned lo = pack2bf(s.v[j * 2 + c].x, s.v[j * 2 + c].y);
        unsigned hi = pack2bf(s.v[j * 2 + c].z, s.v[j * 2 + c].w);
        *(unsigned long long*)(Ab + aoffb[j][c]) =
            (unsigned long long)lo | ((unsigned long long)hi << 32);
      }
  };
  // one BK=64 step: h = which 128-B half of the A chunk
  auto computeStep = [&](const char* Ab, int h, const char* Bb) {
#pragma unroll
    for (int kh = 0; kh < 2; kh++) {
      s16x8 af[4], bf[4];
#pragma unroll
      for (int mt = 0; mt < 4; mt++) {
        int r = wm * 64 + mt * 16 + lr;
        int off = r * 256 + ((h * 128 + kh * 64 + lk * 16) ^ ((r & 7) << 4));
        af[mt] = *(const s16x8*)(Ab + off);
      }
#pragma unroll
      for (int nt = 0; nt < 4; nt++) {
        int n = wn * 64 + nt * 16 + lr;
        int off = n * 128 + ((kh * 64 + lk * 16) ^ ((n & 7) << 4));
        bf[nt] = *(const s16x8*)(Bb + off);
      }
#pragma unroll
      for (int mt = 0; mt < 4; mt++)
#pragma unroll
        for (int nt = 0; nt < 4; nt++)
          acc[mt][nt] = __builtin_amdgcn_mfma_f32_16x16x32_bf16(af[mt], bf[nt],
                                                                acc[mt][nt], 0, 0, 0);
    }
  };

#define BAR_V(N)                                                   \
  asm volatile("s_waitcnt vmcnt(" #N ") lgkmcnt(0)" ::: "memory"); \
  __builtin_amdgcn_s_barrier();                                    \
  __builtin_amdgcn_sched_barrier(0);

  // prologue: A(0) first so writeA's wait keeps B(0) in flight
  issueA(0, avP);
  issueB(0, Bb0);
  writeA(avP, Ab0);          // waits A(0) only (vmcnt keeps B(0))
  issueA(1, avQ);
  BAR_V(8)                   // drain B(0); keep A(1)

  // main loop: 31 iterations x 4 steps; steps 0..123, chunks 0..61 computed
  for (int i = 0; i < 31; i++) {
    // even step s=4i: chunk 2i in Ab0
    issueB(4 * i + 1, Bb1);
    computeStep(Ab0, 0, Bb0);
    writeA(avQ, Ab1);                    // chunk 2i+1 -> Ab1
    BAR_V(0)                             // only fresh B(s+1) outstanding
    // odd step s=4i+1
    issueB(4 * i + 2, Bb0);
    issueA(2 * i + 2, avP);
    computeStep(Ab0, 1, Bb1);
    BAR_V(8)                             // drain B(s+1); keep A(u+2)
    // even step s=4i+2: chunk 2i+1 in Ab1
    issueB(4 * i + 3, Bb1);
    computeStep(Ab1, 0, Bb0);
    writeA(avP, Ab0);                    // chunk 2i+2 -> Ab0
    BAR_V(0)
    // odd step s=4i+3
    issueB(4 * i + 4, Bb0);
    issueA(2 * i + 3, avQ);
    computeStep(Ab1, 1, Bb1);
    BAR_V(8)
  }
  // tail: steps 124..127 (chunks 62 in Ab0, 63 via avQ)
  issueB(125, Bb1);
  computeStep(Ab0, 0, Bb0);
  writeA(avQ, Ab1);                      // chunk 63 -> Ab1
  BAR_V(0)
  issueB(126, Bb0);
  computeStep(Ab0, 1, Bb1);
  BAR_V(0)
  issueB(127, Bb1);
  computeStep(Ab1, 0, Bb0);
  BAR_V(0)
  computeStep(Ab1, 1, Bb1);
#undef BAR_V

#pragma unroll
  for (int mt = 0; mt < 4; mt++) {
    int rbase = m0 + wm * 64 + mt * 16 + lk * 4;
#pragma unroll
    for (int nt = 0; nt < 4; nt++) {
      int c = wn * 64 + nt * 16 + lr;
#pragma unroll
      for (int j = 0; j < 4; j++)
        __builtin_nontemporal_store(acc[mt][nt][j],
                                    out + (size_t)(rbase + j) * DIM + c);
    }
  }
}

// ---------------- fused MLP (r11-exact) ----------------
__global__ __launch_bounds__(512) void mlp_fused(const float* __restrict__ P,
                                                 const unsigned short* __restrict__ WgT,
                                                 const float* __restrict__ bg,
                                                 const unsigned short* __restrict__ uW1T,
                                                 const unsigned short* __restrict__ iW1T,
                                                 const float* __restrict__ ub1,
                                                 const float* __restrict__ ib1,
                                                 const unsigned short* __restrict__ uW2T,
                                                 const unsigned short* __restrict__ iW2T,
                                                 const float* __restrict__ ub2,
                                                 const float* __restrict__ ib2,
                                                 unsigned short* __restrict__ un) {
  __shared__ char smem[96 * 1024];
  char* const Xa = smem;              // activation A [64 rows][512 B] bf16, 32 KB
  char* const Xb = smem + 32 * 1024;  // activation B [64][512 B], 32 KB
  char* const Bb = smem + 64 * 1024;  // weight stage [256][64] bf16, 32 KB
  __shared__ float rs[64][4];

  const int tid = threadIdx.x, l = tid & 63, w = tid >> 6;
  const int wm = w >> 2, wn = w & 3;  // wave tile 32x64
  const int m0 = blockIdx.x * 64;
  const unsigned short* W1 = (m0 < NUSER) ? uW1T : iW1T;
  const float* b1 = (m0 < NUSER) ? ub1 : ib1;
  const unsigned short* W2 = (m0 < NUSER) ? uW2T : iW2T;
  const float* b2 = (m0 < NUSER) ? ub2 : ib2;
  const int arow = tid >> 4, ac4 = tid & 15;
  const int bn = tid >> 3, bg_ = tid & 7;
  const int lr = l & 15, lk = l >> 4;

  // stage phase-1 input: rows m0..m0+63 of (P0+P1) -> Xa (bf16, swizzled)
#pragma unroll
  for (int step = 0; step < 4; step++)
#pragma unroll
    for (int i = 0; i < 2; i++) {
      int r = i * 32 + arow;
      size_t gi = (size_t)(m0 + r) * DIM + step * 64 + ac4 * 4;
      f32x4 v = *(const f32x4*)(P + gi);
      v += *(const f32x4*)(P + (size_t)NTOT * DIM + gi);
      unsigned lo = pack2bf(v.x, v.y);
      unsigned hi = pack2bf(v.z, v.w);
      int off = r * 512 + ((step * 128 + ac4 * 8) ^ ((r & 7) << 4));
      *(unsigned long long*)(Xa + off) =
          (unsigned long long)lo | ((unsigned long long)hi << 32);
    }

  f32x4 zero = {0.f, 0.f, 0.f, 0.f};
  f32x4 acc[2][4];

  auto phase = [&](const char* Alds, const unsigned short* WT) {
#pragma unroll
    for (int i = 0; i < 2; i++)
#pragma unroll
      for (int j = 0; j < 4; j++) acc[i][j] = zero;
    for (int step = 0; step < 4; step++) {
#pragma unroll
      for (int i = 0; i < 4; i++) {
        int n = i * 64 + bn;
        i32x4 v = *(const i32x4*)(WT + (size_t)n * DIM + step * 64 + bg_ * 8);
        int off = (n * 128 + bg_ * 16) ^ ((n & 7) << 4);
        *(i32x4*)(Bb + off) = v;
      }
      __syncthreads();
#pragma unroll
      for (int kh = 0; kh < 2; kh++) {
        s16x8 af[2], bfr[4];
#pragma unroll
        for (int mt = 0; mt < 2; mt++) {
          int r = wm * 32 + mt * 16 + lr;
          int off = r * 512 + ((step * 128 + kh * 64 + lk * 16) ^ ((r & 7) << 4));
          af[mt] = *(const s16x8*)(Alds + off);
        }
#pragma unroll
        for (int nt = 0; nt < 4; nt++) {
          int n = wn * 64 + nt * 16 + lr;
          int off = (n * 128 + kh * 64 + lk * 16) ^ ((n & 7) << 4);
          bfr[nt] = *(const s16x8*)(Bb + off);
        }
#pragma unroll
        for (int mt = 0; mt < 2; mt++)
#pragma unroll
          for (int nt = 0; nt < 4; nt++)
            acc[mt][nt] = __builtin_amdgcn_mfma_f32_16x16x32_bf16(af[mt], bfr[nt],
                                                                  acc[mt][nt], 0, 0, 0);
      }
      __syncthreads();
    }
  };
  auto reluToLds = [&](const float* bias, char* dst) {
#pragma unroll
    for (int nt = 0; nt < 4; nt++) {
      int c = wn * 64 + nt * 16 + lr;
      float b = bias[c];
#pragma unroll
      for (int mt = 0; mt < 2; mt++) {
        int rbase = wm * 32 + mt * 16 + lk * 4;
#pragma unroll
        for (int j = 0; j < 4; j++) {
          float v = fmaxf(acc[mt][nt][j] + b, 0.f);
          int row = rbase + j;
          int off = row * 512 + ((c * 2) ^ ((row & 7) << 4));
          *(unsigned short*)(dst + off) = f2bf(v);
        }
      }
    }
  };

  __syncthreads();
  phase(Xa, WgT);
  reluToLds(bg, Xb);
  __syncthreads();
  phase(Xb, W1);
  reluToLds(b1, Xa);
  __syncthreads();
  phase(Xa, W2);

  float uval[2][4][4];
  float p[2][4];
#pragma unroll
  for (int mt = 0; mt < 2; mt++)
#pragma unroll
    for (int j = 0; j < 4; j++) p[mt][j] = 0.f;
#pragma unroll
  for (int nt = 0; nt < 4; nt++) {
    int c = wn * 64 + nt * 16 + lr;
    float b = b2[c];
#pragma unroll
    for (int mt = 0; mt < 2; mt++)
#pragma unroll
      for (int j = 0; j < 4; j++) {
        float v = acc[mt][nt][j] + b;
        uval[mt][nt][j] = v;
        p[mt][j] += v * v;
      }
  }
#pragma unroll
  for (int d = 1; d < 16; d <<= 1)
#pragma unroll
    for (int mt = 0; mt < 2; mt++)
#pragma unroll
      for (int j = 0; j < 4; j++) p[mt][j] += __shfl_xor(p[mt][j], d, 64);
  if (lr == 0) {
#pragma unroll
    for (int mt = 0; mt < 2; mt++)
#pragma unroll
      for (int j = 0; j < 4; j++) rs[wm * 32 + mt * 16 + lk * 4 + j][wn] = p[mt][j];
  }
  __syncthreads();
#pragma unroll
  for (int mt = 0; mt < 2; mt++) {
    int rl = wm * 32 + mt * 16 + lk * 4;
#pragma unroll
    for (int j = 0; j < 4; j++) {
      float tot = rs[rl + j][0] + rs[rl + j][1] + rs[rl + j][2] + rs[rl + j][3];
      float inv = 1.f / fmaxf(sqrtf(tot), 1e-8f);
#pragma unroll
      for (int nt = 0; nt < 4; nt++) {
        int c = wn * 64 + nt * 16 + lr;
        un[(size_t)(m0 + rl + j) * DIM + c] = f2bf(uval[mt][nt][j] * inv);
      }
    }
  }
}

// ---------------- sim = clip(un @ itn^T) (r6-exact) ----------------
__global__ __launch_bounds__(512) void simk(const unsigned short* __restrict__ UN,
                                            float* __restrict__ out) {
  __shared__ char smem[128 * 1024];
  char* Ab = smem;              // [128][256] bf16 64KB
  char* Bb = smem + 64 * 1024;  // [128][256] bf16 64KB
  const int tid = threadIdx.x, l = tid & 63, w = tid >> 6;
  const int wm = w >> 2, wn = w & 3;  // wave tile 64x32
  const int lin = blockIdx.x + (blockIdx.y << 6);
  const int xcd = lin & 7, slot = lin >> 3;
  const int nblk = xcd * 8 + (slot & 7);
  const int mblk = slot >> 3;
  const int m0 = mblk * 128, n0 = nblk * 128;
  const int lr = l & 15, lk = l >> 4;
  const int sr = tid >> 5, sg = tid & 31;

#pragma unroll
  for (int i = 0; i < 8; i++) {
    int r = i * 16 + sr;
    i32x4 va = *(const i32x4*)(UN + (size_t)(m0 + r) * DIM + sg * 8);
    i32x4 vb = *(const i32x4*)(UN + (size_t)(NUSER + n0 + r) * DIM + sg * 8);
    int off = (r * 512 + sg * 16) ^ ((r & 7) << 4);
    *(i32x4*)(Ab + off) = va;
    *(i32x4*)(Bb + off) = vb;
  }
  __syncthreads();

  f32x4 zero = {0.f, 0.f, 0.f, 0.f};
  f32x4 acc[4][2];
#pragma unroll
  for (int i = 0; i < 4; i++)
#pragma unroll
    for (int j = 0; j < 2; j++) acc[i][j] = zero;

#pragma unroll
  for (int ks = 0; ks < 8; ks++) {
    s16x8 af[4], bfr[2];
#pragma unroll
    for (int mt = 0; mt < 4; mt++) {
      int r = wm * 64 + mt * 16 + lr;
      int off = (r * 512 + ks * 64 + lk * 16) ^ ((r & 7) << 4);
      af[mt] = *(const s16x8*)(Ab + off);
    }
#pragma unroll
    for (int nt = 0; nt < 2; nt++) {
      int n = wn * 32 + nt * 16 + lr;
      int off = (n * 512 + ks * 64 + lk * 16) ^ ((n & 7) << 4);
      bfr[nt] = *(const s16x8*)(Bb + off);
    }
#pragma unroll
    for (int mt = 0; mt < 4; mt++)
#pragma unroll
      for (int nt = 0; nt < 2; nt++)
        acc[mt][nt] = __builtin_amdgcn_mfma_f32_16x16x32_bf16(af[mt], bfr[nt],
                                                              acc[mt][nt], 0, 0, 0);
  }

#pragma unroll
  for (int mt = 0; mt < 4; mt++) {
    int rbase = m0 + wm * 64 + mt * 16 + lk * 4;
#pragma unroll
    for (int nt = 0; nt < 2; nt++) {
      int c = n0 + wn * 32 + nt * 16 + lr;
#pragma unroll
      for (int j = 0; j < 4; j++) {
        float v = fminf(fmaxf(acc[mt][nt][j], 1e-6f), 1.0f);
        __builtin_nontemporal_store(v, out + (size_t)(rbase + j) * 8192 + c);
      }
    }
  }
}

extern "C" void kernel_launch(void* const* d_in, const int* in_sizes, int n_in,
                              void* d_out, int out_size, void* d_ws, size_t ws_size,
                              hipStream_t stream) {
  const float* A    = (const float*)d_in[0];
  const float* feat = (const float*)d_in[1];
  const float* Wg   = (const float*)d_in[2];
  const float* bg   = (const float*)d_in[3];
  const float* uW1  = (const float*)d_in[4];
  const float* ub1  = (const float*)d_in[5];
  const float* uW2  = (const float*)d_in[6];
  const float* ub2  = (const float*)d_in[7];
  const float* iW1  = (const float*)d_in[8];
  const float* ib1  = (const float*)d_in[9];
  const float* iW2  = (const float*)d_in[10];
  const float* ib2  = (const float*)d_in[11];
  float* out = (float*)d_out;
  char* ob = (char*)d_out;

  // transient scratch inside d_out (dead before simk overwrites everything)
  float*          F1p  = (float*)(ob + 0);                 // 32 MiB: [2][16384][256] f32
  unsigned short* Ft   = (unsigned short*)(ob + 33554432); // 8 MiB: [256][16384] bf16
  unsigned short* WT5  = (unsigned short*)(ob + 41943040); // 5 x 128 KiB
  unsigned short* WgT  = WT5;
  unsigned short* uW1T = WT5 + 1 * 65536;
  unsigned short* uW2T = WT5 + 2 * 65536;
  unsigned short* iW1T = WT5 + 3 * 65536;
  unsigned short* iW2T = WT5 + 4 * 65536;
  unsigned short* UN   = (unsigned short*)d_ws;            // 8 MiB, survives into simk

  transpose_cvt<<<dim3(256, 4), 256, 0, stream>>>(feat, Ft, NTOT, DIM);
  transpose_w5<<<dim3(4, 4, 5), 256, 0, stream>>>(Wg, uW1, uW2, iW1, iW2, WT5);

  gemm1<<<dim3(256), 512, 0, stream>>>(A, Ft, F1p);
  mlp_fused<<<dim3(256), 512, 0, stream>>>(F1p, WgT, bg, uW1T, iW1T, ub1, ib1,
                                           uW2T, iW2T, ub2, ib2, UN);
  simk<<<dim3(64, 64), 512, 0, stream>>>(UN, out);
}

// Round 13
// 320.509 us; speedup vs baseline: 1.1294x; 1.1294x over previous
//
#include <hip/hip_runtime.h>
#include <hip/hip_bf16.h>

using f32x4 = __attribute__((ext_vector_type(4))) float;
using s16x8 = __attribute__((ext_vector_type(8))) short;
using i32x4 = __attribute__((ext_vector_type(4))) int;

#define NTOT 16384
#define NUSER 8192
#define DIM 256

__device__ __forceinline__ unsigned short f2bf(float f) {
  union { float f; unsigned u; } v; v.f = f;
  unsigned r = v.u + 0x7FFFu + ((v.u >> 16) & 1u);   // RNE
  return (unsigned short)(r >> 16);
}

__device__ __forceinline__ unsigned pack2bf(float x, float y) {
  float2 t; t.x = x; t.y = y;
  __hip_bfloat162 h = __float22bfloat162_rn(t);
  union { __hip_bfloat162 h; unsigned u; } cv; cv.h = h;
  return cv.u;
}

__device__ __forceinline__ void gload_lds16(const void* g, void* l) {
  __builtin_amdgcn_global_load_lds(
      (const __attribute__((address_space(1))) unsigned int*)g,
      (__attribute__((address_space(3))) unsigned int*)l, 16, 0, 0);
}

// ---------------- transpose + f32->bf16: dst[N][K] = src[K][N] ----------------
__global__ __launch_bounds__(256) void transpose_cvt(const float* __restrict__ src,
                                                     unsigned short* __restrict__ dst,
                                                     int K, int N) {
  __shared__ float tile[64][65];
  const int k0 = blockIdx.x * 64, n0 = blockIdx.y * 64;
  const int t = threadIdx.x;
#pragma unroll
  for (int i = 0; i < 16; i++) {
    int idx = i * 256 + t, r = idx >> 6, c = idx & 63;
    tile[r][c] = src[(size_t)(k0 + r) * N + n0 + c];
  }
  __syncthreads();
#pragma unroll
  for (int i = 0; i < 16; i++) {
    int idx = i * 256 + t, r = idx >> 6, c = idx & 63;
    dst[(size_t)(n0 + r) * K + k0 + c] = f2bf(tile[c][r]);
  }
}

// 5 square 256x256 weights in one launch
__global__ __launch_bounds__(256) void transpose_w5(const float* __restrict__ w0,
                                                    const float* __restrict__ w1,
                                                    const float* __restrict__ w2,
                                                    const float* __restrict__ w3,
                                                    const float* __restrict__ w4,
                                                    unsigned short* __restrict__ dstbase) {
  __shared__ float tile[64][65];
  const float* srcs[5] = {w0, w1, w2, w3, w4};
  const float* src = srcs[blockIdx.z];
  unsigned short* dst = dstbase + (size_t)blockIdx.z * 65536;
  const int k0 = blockIdx.x * 64, n0 = blockIdx.y * 64;
  const int t = threadIdx.x;
#pragma unroll
  for (int i = 0; i < 16; i++) {
    int idx = i * 256 + t, r = idx >> 6, c = idx & 63;
    tile[r][c] = src[(size_t)(k0 + r) * 256 + n0 + c];
  }
  __syncthreads();
#pragma unroll
  for (int i = 0; i < 16; i++) {
    int idx = i * 256 + t, r = idx >> 6, c = idx & 63;
    dst[(size_t)(n0 + r) * 256 + k0 + c] = f2bf(tile[c][r]);
  }
}

// ---------------- gemm1 (r6-exact): F1p[s] = A[:, sK:] @ feat[sK:, :] --------
__global__ __launch_bounds__(512) void gemm1(const float* __restrict__ A,
                                             const unsigned short* __restrict__ Ft,
                                             float* __restrict__ F1p) {
  __shared__ char smem[144 * 1024];
  char* const Ab0 = smem;                 // [128][64] bf16, 16 KB each
  char* const Ab1 = smem + 16 * 1024;
  char* const Ab2 = smem + 32 * 1024;
  char* const Bb0 = smem + 48 * 1024;     // [256][64] bf16, 32 KB each
  char* const Bb1 = smem + 80 * 1024;
  char* const Bb2 = smem + 112 * 1024;

  const int tid = threadIdx.x;
  const int l = tid & 63, w = tid >> 6;
  const int wm = w >> 2, wn = w & 3;      // 2x4 waves, wave tile 64x64
  const int lr = l & 15, lk = l >> 4;

  const int lin = blockIdx.x;             // 0..255
  const int xcd = lin & 7, slot = lin >> 3;   // slot 0..31
  const int ks = xcd >> 2;                // 0..1
  const int mblk = (xcd & 3) * 32 + slot; // 0..127
  const int m0 = mblk * 128;
  const size_t ks0 = (size_t)ks * 8192;
  float* out = F1p + (size_t)ks * NTOT * DIM;

  const int arow = tid >> 4, ac16 = tid & 15;   // row-in-32, 16B chunk
  const float* asrc = A + (size_t)(m0 + arow) * NTOT + ks0 + ac16 * 4;
  int aoff[4];
#pragma unroll
  for (int j = 0; j < 4; j++) {
    int r = j * 32 + arow;
    aoff[j] = r * 128 + ((ac16 * 8) ^ ((r & 7) << 4));
  }

  const int brin = l >> 3;
  const int bldso = w * 4096;
  const char* bsrc = (const char*)Ft + (size_t)(w * 32 + brin) * (NTOT * 2) +
                     ks0 * 2 + (((l & 7) * 16) ^ (brin << 4));

  f32x4 zero = {0.f, 0.f, 0.f, 0.f};
  f32x4 acc[4][4];
#pragma unroll
  for (int i = 0; i < 4; i++)
#pragma unroll
    for (int j = 0; j < 4; j++) acc[i][j] = zero;

  struct AQuad { f32x4 v[4]; };
  AQuad av0, av1, av2;

  auto issueB = [&](int t, char* Bb) {
#pragma unroll
    for (int i = 0; i < 4; i++)
      gload_lds16(bsrc + (size_t)i * 8 * (NTOT * 2) + t * 128,
                  Bb + bldso + i * 1024);
  };
  auto loadA = [&](int t, AQuad& s) {
#pragma unroll
    for (int j = 0; j < 4; j++)
      s.v[j] = __builtin_nontemporal_load(
          (const f32x4*)(asrc + (size_t)j * 32 * NTOT + t * 64));
  };
  auto writeA = [&](const AQuad& s, char* Ab) {
#pragma unroll
    for (int j = 0; j < 4; j++) {
      unsigned lo = pack2bf(s.v[j].x, s.v[j].y);
      unsigned hi = pack2bf(s.v[j].z, s.v[j].w);
      *(unsigned long long*)(Ab + aoff[j]) =
          (unsigned long long)lo | ((unsigned long long)hi << 32);
    }
  };
  auto compute = [&](const char* Ab, const char* Bb) {
#pragma unroll
    for (int kh = 0; kh < 2; kh++) {
      s16x8 af[4], bf[4];
#pragma unroll
      for (int mt = 0; mt < 4; mt++) {
        int r = wm * 64 + mt * 16 + lr;
        int off = r * 128 + ((kh * 64 + lk * 16) ^ ((r & 7) << 4));
        af[mt] = *(const s16x8*)(Ab + off);
      }
#pragma unroll
      for (int nt = 0; nt < 4; nt++) {
        int n = wn * 64 + nt * 16 + lr;
        int off = n * 128 + ((kh * 64 + lk * 16) ^ ((n & 7) << 4));
        bf[nt] = *(const s16x8*)(Bb + off);
      }
#pragma unroll
      for (int mt = 0; mt < 4; mt++)
#pragma unroll
        for (int nt = 0; nt < 4; nt++)
          acc[mt][nt] = __builtin_amdgcn_mfma_f32_16x16x32_bf16(af[mt], bf[nt],
                                                                acc[mt][nt], 0, 0, 0);
    }
  };

#define STEP_BAR(N)                                                \
  asm volatile("s_waitcnt vmcnt(" #N ") lgkmcnt(0)" ::: "memory"); \
  __builtin_amdgcn_s_barrier();                                    \
  __builtin_amdgcn_sched_barrier(0);

  issueB(0, Bb0);
  loadA(0, av0);
  issueB(1, Bb1);
  loadA(1, av1);
  writeA(av0, Ab0);
  STEP_BAR(8)

  for (int t = 0; t < 126; t += 3) {
    issueB(t + 2, Bb2);
    loadA(t + 2, av2);
    compute(Ab0, Bb0);
    writeA(av1, Ab1);
    STEP_BAR(8)
    issueB(t + 3, Bb0);
    loadA(t + 3, av0);
    compute(Ab1, Bb1);
    writeA(av2, Ab2);
    STEP_BAR(8)
    issueB(t + 4, Bb1);
    loadA(t + 4, av1);
    compute(Ab2, Bb2);
    writeA(av0, Ab0);
    STEP_BAR(8)
  }
  compute(Ab0, Bb0);
  writeA(av1, Ab1);
  STEP_BAR(0)
  compute(Ab1, Bb1);
#undef STEP_BAR

#pragma unroll
  for (int mt = 0; mt < 4; mt++) {
    int rbase = m0 + wm * 64 + mt * 16 + lk * 4;
#pragma unroll
    for (int nt = 0; nt < 4; nt++) {
      int c = wn * 64 + nt * 16 + lr;
#pragma unroll
      for (int j = 0; j < 4; j++)
        __builtin_nontemporal_store(acc[mt][nt][j],
                                    out + (size_t)(rbase + j) * DIM + c);
    }
  }
}

// ---------------- fused MLP (r11-exact) ----------------
__global__ __launch_bounds__(512) void mlp_fused(const float* __restrict__ P,
                                                 const unsigned short* __restrict__ WgT,
                                                 const float* __restrict__ bg,
                                                 const unsigned short* __restrict__ uW1T,
                                                 const unsigned short* __restrict__ iW1T,
                                                 const float* __restrict__ ub1,
                                                 const float* __restrict__ ib1,
                                                 const unsigned short* __restrict__ uW2T,
                                                 const unsigned short* __restrict__ iW2T,
                                                 const float* __restrict__ ub2,
                                                 const float* __restrict__ ib2,
                                                 unsigned short* __restrict__ un) {
  __shared__ char smem[96 * 1024];
  char* const Xa = smem;              // activation A [64 rows][512 B] bf16, 32 KB
  char* const Xb = smem + 32 * 1024;  // activation B [64][512 B], 32 KB
  char* const Bb = smem + 64 * 1024;  // weight stage [256][64] bf16, 32 KB
  __shared__ float rs[64][4];

  const int tid = threadIdx.x, l = tid & 63, w = tid >> 6;
  const int wm = w >> 2, wn = w & 3;  // wave tile 32x64
  const int m0 = blockIdx.x * 64;
  const unsigned short* W1 = (m0 < NUSER) ? uW1T : iW1T;
  const float* b1 = (m0 < NUSER) ? ub1 : ib1;
  const unsigned short* W2 = (m0 < NUSER) ? uW2T : iW2T;
  const float* b2 = (m0 < NUSER) ? ub2 : ib2;
  const int arow = tid >> 4, ac4 = tid & 15;
  const int bn = tid >> 3, bg_ = tid & 7;
  const int lr = l & 15, lk = l >> 4;

  // stage phase-1 input: rows m0..m0+63 of (P0+P1) -> Xa (bf16, swizzled)
#pragma unroll
  for (int step = 0; step < 4; step++)
#pragma unroll
    for (int i = 0; i < 2; i++) {
      int r = i * 32 + arow;
      size_t gi = (size_t)(m0 + r) * DIM + step * 64 + ac4 * 4;
      f32x4 v = *(const f32x4*)(P + gi);
      v += *(const f32x4*)(P + (size_t)NTOT * DIM + gi);
      unsigned lo = pack2bf(v.x, v.y);
      unsigned hi = pack2bf(v.z, v.w);
      int off = r * 512 + ((step * 128 + ac4 * 8) ^ ((r & 7) << 4));
      *(unsigned long long*)(Xa + off) =
          (unsigned long long)lo | ((unsigned long long)hi << 32);
    }

  f32x4 zero = {0.f, 0.f, 0.f, 0.f};
  f32x4 acc[2][4];

  auto phase = [&](const char* Alds, const unsigned short* WT) {
#pragma unroll
    for (int i = 0; i < 2; i++)
#pragma unroll
      for (int j = 0; j < 4; j++) acc[i][j] = zero;
    for (int step = 0; step < 4; step++) {
#pragma unroll
      for (int i = 0; i < 4; i++) {
        int n = i * 64 + bn;
        i32x4 v = *(const i32x4*)(WT + (size_t)n * DIM + step * 64 + bg_ * 8);
        int off = (n * 128 + bg_ * 16) ^ ((n & 7) << 4);
        *(i32x4*)(Bb + off) = v;
      }
      __syncthreads();
#pragma unroll
      for (int kh = 0; kh < 2; kh++) {
        s16x8 af[2], bfr[4];
#pragma unroll
        for (int mt = 0; mt < 2; mt++) {
          int r = wm * 32 + mt * 16 + lr;
          int off = r * 512 + ((step * 128 + kh * 64 + lk * 16) ^ ((r & 7) << 4));
          af[mt] = *(const s16x8*)(Alds + off);
        }
#pragma unroll
        for (int nt = 0; nt < 4; nt++) {
          int n = wn * 64 + nt * 16 + lr;
          int off = (n * 128 + kh * 64 + lk * 16) ^ ((n & 7) << 4);
          bfr[nt] = *(const s16x8*)(Bb + off);
        }
#pragma unroll
        for (int mt = 0; mt < 2; mt++)
#pragma unroll
          for (int nt = 0; nt < 4; nt++)
            acc[mt][nt] = __builtin_amdgcn_mfma_f32_16x16x32_bf16(af[mt], bfr[nt],
                                                                  acc[mt][nt], 0, 0, 0);
      }
      __syncthreads();
    }
  };
  auto reluToLds = [&](const float* bias, char* dst) {
#pragma unroll
    for (int nt = 0; nt < 4; nt++) {
      int c = wn * 64 + nt * 16 + lr;
      float b = bias[c];
#pragma unroll
      for (int mt = 0; mt < 2; mt++) {
        int rbase = wm * 32 + mt * 16 + lk * 4;
#pragma unroll
        for (int j = 0; j < 4; j++) {
          float v = fmaxf(acc[mt][nt][j] + b, 0.f);
          int row = rbase + j;
          int off = row * 512 + ((c * 2) ^ ((row & 7) << 4));
          *(unsigned short*)(dst + off) = f2bf(v);
        }
      }
    }
  };

  __syncthreads();
  phase(Xa, WgT);
  reluToLds(bg, Xb);
  __syncthreads();
  phase(Xb, W1);
  reluToLds(b1, Xa);
  __syncthreads();
  phase(Xa, W2);

  float uval[2][4][4];
  float p[2][4];
#pragma unroll
  for (int mt = 0; mt < 2; mt++)
#pragma unroll
    for (int j = 0; j < 4; j++) p[mt][j] = 0.f;
#pragma unroll
  for (int nt = 0; nt < 4; nt++) {
    int c = wn * 64 + nt * 16 + lr;
    float b = b2[c];
#pragma unroll
    for (int mt = 0; mt < 2; mt++)
#pragma unroll
      for (int j = 0; j < 4; j++) {
        float v = acc[mt][nt][j] + b;
        uval[mt][nt][j] = v;
        p[mt][j] += v * v;
      }
  }
#pragma unroll
  for (int d = 1; d < 16; d <<= 1)
#pragma unroll
    for (int mt = 0; mt < 2; mt++)
#pragma unroll
      for (int j = 0; j < 4; j++) p[mt][j] += __shfl_xor(p[mt][j], d, 64);
  if (lr == 0) {
#pragma unroll
    for (int mt = 0; mt < 2; mt++)
#pragma unroll
      for (int j = 0; j < 4; j++) rs[wm * 32 + mt * 16 + lk * 4 + j][wn] = p[mt][j];
  }
  __syncthreads();
#pragma unroll
  for (int mt = 0; mt < 2; mt++) {
    int rl = wm * 32 + mt * 16 + lk * 4;
#pragma unroll
    for (int j = 0; j < 4; j++) {
      float tot = rs[rl + j][0] + rs[rl + j][1] + rs[rl + j][2] + rs[rl + j][3];
      float inv = 1.f / fmaxf(sqrtf(tot), 1e-8f);
#pragma unroll
      for (int nt = 0; nt < 4; nt++) {
        int c = wn * 64 + nt * 16 + lr;
        un[(size_t)(m0 + rl + j) * DIM + c] = f2bf(uval[mt][nt][j] * inv);
      }
    }
  }
}

// ---------------- sim = clip(un @ itn^T) (r6-exact) ----------------
__global__ __launch_bounds__(512) void simk(const unsigned short* __restrict__ UN,
                                            float* __restrict__ out) {
  __shared__ char smem[128 * 1024];
  char* Ab = smem;              // [128][256] bf16 64KB
  char* Bb = smem + 64 * 1024;  // [128][256] bf16 64KB
  const int tid = threadIdx.x, l = tid & 63, w = tid >> 6;
  const int wm = w >> 2, wn = w & 3;  // wave tile 64x32
  const int lin = blockIdx.x + (blockIdx.y << 6);
  const int xcd = lin & 7, slot = lin >> 3;
  const int nblk = xcd * 8 + (slot & 7);
  const int mblk = slot >> 3;
  const int m0 = mblk * 128, n0 = nblk * 128;
  const int lr = l & 15, lk = l >> 4;
  const int sr = tid >> 5, sg = tid & 31;

#pragma unroll
  for (int i = 0; i < 8; i++) {
    int r = i * 16 + sr;
    i32x4 va = *(const i32x4*)(UN + (size_t)(m0 + r) * DIM + sg * 8);
    i32x4 vb = *(const i32x4*)(UN + (size_t)(NUSER + n0 + r) * DIM + sg * 8);
    int off = (r * 512 + sg * 16) ^ ((r & 7) << 4);
    *(i32x4*)(Ab + off) = va;
    *(i32x4*)(Bb + off) = vb;
  }
  __syncthreads();

  f32x4 zero = {0.f, 0.f, 0.f, 0.f};
  f32x4 acc[4][2];
#pragma unroll
  for (int i = 0; i < 4; i++)
#pragma unroll
    for (int j = 0; j < 2; j++) acc[i][j] = zero;

#pragma unroll
  for (int ks = 0; ks < 8; ks++) {
    s16x8 af[4], bfr[2];
#pragma unroll
    for (int mt = 0; mt < 4; mt++) {
      int r = wm * 64 + mt * 16 + lr;
      int off = (r * 512 + ks * 64 + lk * 16) ^ ((r & 7) << 4);
      af[mt] = *(const s16x8*)(Ab + off);
    }
#pragma unroll
    for (int nt = 0; nt < 2; nt++) {
      int n = wn * 32 + nt * 16 + lr;
      int off = (n * 512 + ks * 64 + lk * 16) ^ ((n & 7) << 4);
      bfr[nt] = *(const s16x8*)(Bb + off);
    }
#pragma unroll
    for (int mt = 0; mt < 4; mt++)
#pragma unroll
      for (int nt = 0; nt < 2; nt++)
        acc[mt][nt] = __builtin_amdgcn_mfma_f32_16x16x32_bf16(af[mt], bfr[nt],
                                                              acc[mt][nt], 0, 0, 0);
  }

#pragma unroll
  for (int mt = 0; mt < 4; mt++) {
    int rbase = m0 + wm * 64 + mt * 16 + lk * 4;
#pragma unroll
    for (int nt = 0; nt < 2; nt++) {
      int c = n0 + wn * 32 + nt * 16 + lr;
#pragma unroll
      for (int j = 0; j < 4; j++) {
        float v = fminf(fmaxf(acc[mt][nt][j], 1e-6f), 1.0f);
        __builtin_nontemporal_store(v, out + (size_t)(rbase + j) * 8192 + c);
      }
    }
  }
}

extern "C" void kernel_launch(void* const* d_in, const int* in_sizes, int n_in,
                              void* d_out, int out_size, void* d_ws, size_t ws_size,
                              hipStream_t stream) {
  const float* A    = (const float*)d_in[0];
  const float* feat = (const float*)d_in[1];
  const float* Wg   = (const float*)d_in[2];
  const float* bg   = (const float*)d_in[3];
  const float* uW1  = (const float*)d_in[4];
  const float* ub1  = (const float*)d_in[5];
  const float* uW2  = (const float*)d_in[6];
  const float* ub2  = (const float*)d_in[7];
  const float* iW1  = (const float*)d_in[8];
  const float* ib1  = (const float*)d_in[9];
  const float* iW2  = (const float*)d_in[10];
  const float* ib2  = (const float*)d_in[11];
  float* out = (float*)d_out;
  char* ob = (char*)d_out;

  // transient scratch inside d_out (dead before simk overwrites everything)
  float*          F1p  = (float*)(ob + 0);                 // 32 MiB: [2][16384][256] f32
  unsigned short* Ft   = (unsigned short*)(ob + 33554432); // 8 MiB: [256][16384] bf16
  unsigned short* WT5  = (unsigned short*)(ob + 41943040); // 5 x 128 KiB
  unsigned short* WgT  = WT5;
  unsigned short* uW1T = WT5 + 1 * 65536;
  unsigned short* uW2T = WT5 + 2 * 65536;
  unsigned short* iW1T = WT5 + 3 * 65536;
  unsigned short* iW2T = WT5 + 4 * 65536;
  unsigned short* UN   = (unsigned short*)d_ws;            // 8 MiB, survives into simk

  transpose_cvt<<<dim3(256, 4), 256, 0, stream>>>(feat, Ft, NTOT, DIM);
  transpose_w5<<<dim3(4, 4, 5), 256, 0, stream>>>(Wg, uW1, uW2, iW1, iW2, WT5);

  gemm1<<<dim3(256), 512, 0, stream>>>(A, Ft, F1p);
  mlp_fused<<<dim3(256), 512, 0, stream>>>(F1p, WgT, bg, uW1T, iW1T, ub1, ib1,
                                           uW2T, iW2T, ub2, ib2, UN);
  simk<<<dim3(64, 64), 512, 0, stream>>>(UN, out);
}